// Round 4
// baseline (207.182 us; speedup 1.0000x reference)
//
#include <hip/hip_runtime.h>
#include <cstdint>
#include <cstddef>

typedef __bf16 bf16x8 __attribute__((ext_vector_type(8)));
typedef __bf16 bf16x2 __attribute__((ext_vector_type(2)));
typedef float f32x4 __attribute__((ext_vector_type(4)));
typedef unsigned short u16x2 __attribute__((ext_vector_type(2)));

constexpr int HH = 1024;   // hidden dim
constexpr int II = 1024;   // intermediate dim
constexpr int KMAX = 2;
constexpr int EMAX = 8;
constexpr int GU_TILES = 24;   // >= 2048/128 + 8
constexpr int DN_TILES = 40;   // >= 2048/64 + 8
constexpr float FALPHA = 1.702f;
constexpr float FLIMIT = 7.0f;

// USE_CVT: gfx950 hardware fp4->bf16 with fused f32 scale. Natural k-order.
// Fallback: perm-table decode (round-3 proven), k-order permuted [0,2,4,6,1,3,5,7].
#if __has_builtin(__builtin_amdgcn_cvt_scalef32_pk_bf16_fp4)
#define USE_CVT 1
#else
#define USE_CVT 0
#endif

// ---- fallback perm decode helpers ----
__device__ __forceinline__ unsigned pk_add16(unsigned a, unsigned b) {
  u16x2 x, y;
  __builtin_memcpy(&x, &a, 4); __builtin_memcpy(&y, &b, 4);
  u16x2 r = x + y;
  unsigned o; __builtin_memcpy(&o, &r, 4); return o;
}
__device__ __forceinline__ int4 decode_chunk(int4 raw, unsigned addk) {
  unsigned p = (unsigned)raw.x | ((unsigned)raw.y << 8) |
               ((unsigned)raw.z << 16) | ((unsigned)raw.w << 24);
  unsigned q = p >> 4;
  unsigned me = p & 0x07070707u, mo = q & 0x07070707u;
  unsigned se = p & 0x08080808u, so = q & 0x08080808u;
  unsigned hiE = __builtin_amdgcn_perm(0x40404040u, 0x3F3F3F14u, me) | (se << 4);
  unsigned hiO = __builtin_amdgcn_perm(0x40404040u, 0x3F3F3F14u, mo) | (so << 4);
  unsigned loE = __builtin_amdgcn_perm(0xC0804000u, 0xC0800000u, me);
  unsigned loO = __builtin_amdgcn_perm(0xC0804000u, 0xC0800000u, mo);
  int4 out;
  out.x = (int)pk_add16(__builtin_amdgcn_perm(hiE, loE, 0x05010400u), addk); // w2:w0
  out.y = (int)pk_add16(__builtin_amdgcn_perm(hiE, loE, 0x07030602u), addk); // w6:w4
  out.z = (int)pk_add16(__builtin_amdgcn_perm(hiO, loO, 0x05010400u), addk); // w3:w1
  out.w = (int)pk_add16(__builtin_amdgcn_perm(hiO, loO, 0x07030602u), addk); // w7:w5
  return out;
}
__device__ __forceinline__ unsigned make_addk(int s) {
  int k = s - 127;
  unsigned t = ((unsigned)(k << 7)) & 0xFFFFu;
  return t | (t << 16);
}

// one chunk (8 fp4 values, inflated int32-per-byte as int4) + e8m0 scale -> bf16x8 fragment
__device__ __forceinline__ bf16x8 decode_frag(int4 raw, int s) {
#if USE_CVT
  unsigned t0 = __builtin_amdgcn_perm((unsigned)raw.y, (unsigned)raw.x, 0x00000400u);
  unsigned t1 = __builtin_amdgcn_perm((unsigned)raw.w, (unsigned)raw.z, 0x00000400u);
  unsigned p  = __builtin_amdgcn_perm(t1, t0, 0x05040100u);
  float scf = __uint_as_float((unsigned)s << 23);   // 2^(s-127), s in [121,130]
  bf16x2 a = __builtin_amdgcn_cvt_scalef32_pk_bf16_fp4(p, scf, 0);
  bf16x2 b = __builtin_amdgcn_cvt_scalef32_pk_bf16_fp4(p, scf, 1);
  bf16x2 c = __builtin_amdgcn_cvt_scalef32_pk_bf16_fp4(p, scf, 2);
  bf16x2 d = __builtin_amdgcn_cvt_scalef32_pk_bf16_fp4(p, scf, 3);
  bf16x8 r;
  r[0]=a[0]; r[1]=a[1]; r[2]=b[0]; r[3]=b[1]; r[4]=c[0]; r[5]=c[1]; r[6]=d[0]; r[7]=d[1];
  return r;
#else
  int4 d4 = decode_chunk(raw, make_addk(s));
  bf16x8 r; __builtin_memcpy(&r, &d4, 16);
  return r;
#endif
}

__device__ __forceinline__ void gll16(const void* g, void* l) {
  __builtin_amdgcn_global_load_lds(
      (const __attribute__((address_space(1))) void*)g,
      (__attribute__((address_space(3))) void*)l, 16, 0, 0);
}

// ---------------- routing ----------------
__global__ void routing_kernel(const float* __restrict__ logits, const int* __restrict__ dk,
                               int T, int E, float* __restrict__ route,
                               int* __restrict__ tidx, float* __restrict__ tw) {
  int t = blockIdx.x * blockDim.x + threadIdx.x;
  if (t >= T) return;
  int kk = *dk; if (kk > KMAX) kk = KMAX; if (kk < 1) kk = 1;
  int EE = E > EMAX ? EMAX : E;
  float v[EMAX]; bool used[EMAX];
  for (int e = 0; e < EE; ++e) { v[e] = logits[t * E + e]; used[e] = false; route[t * E + e] = 0.f; }
  float tv[KMAX]; int ti[KMAX];
  for (int j = 0; j < kk; ++j) {
    float best = -3.4e38f; int bi = 0;
    for (int e = 0; e < EE; ++e) if (!used[e] && v[e] > best) { best = v[e]; bi = e; }
    used[bi] = true; tv[j] = best; ti[j] = bi;
  }
  float mx = tv[0], ssum = 0.f, wj[KMAX];
  for (int j = 0; j < kk; ++j) { wj[j] = __expf(tv[j] - mx); ssum += wj[j]; }
  for (int j = 0; j < kk; ++j) {
    float wv = wj[j] / ssum;
    route[t * E + ti[j]] = wv;
    tidx[t * kk + j] = ti[j];
    tw[t * kk + j] = wv;
  }
}

__global__ void build_lists(const int* __restrict__ tidx, const int* __restrict__ dk,
                            int T, int* __restrict__ lists, int* __restrict__ counts) {
  int e = blockIdx.x;
  int lane = threadIdx.x;  // 64 threads = 1 wave
  int kk = *dk; if (kk > KMAX) kk = KMAX; if (kk < 1) kk = 1;
  int cnt = 0;
  for (int base = 0; base < T; base += 64) {
    int t = base + lane;
    int j = -1;
    if (t < T) {
      for (int q = 0; q < kk; ++q) if (tidx[t * kk + q] == e) j = q;
    }
    unsigned long long m = __ballot(j >= 0);
    if (j >= 0) {
      int pre = __popcll(m & ((1ull << lane) - 1ull));
      lists[e * T + cnt + pre] = (t << 3) | j;
    }
    cnt += __popcll(m);
  }
  if (lane == 0) counts[e] = cnt;
}

__global__ void build_tiles(const int* __restrict__ counts, int E,
                            int* __restrict__ tabGU, int* __restrict__ tabDN) {
  if (threadIdx.x == 0 && blockIdx.x == 0) {
    int g = 0, d = 0;
    for (int e = 0; e < E && e < EMAX; ++e) {
      int c = counts[e];
      for (int m = 0; m * 128 < c && g < GU_TILES; ++m) tabGU[g++] = (e << 16) | m;
      for (int m = 0; m * 64 < c && d < DN_TILES; ++m) tabDN[d++] = (e << 16) | m;
    }
    for (; g < GU_TILES; ++g) tabGU[g] = -1;
    for (; d < DN_TILES; ++d) tabDN[d] = -1;
  }
}

// ---------------- hs fp32 -> bf16 ----------------
__global__ void convert_hs(const float* __restrict__ hs, __bf16* __restrict__ hsb, int n8) {
  int g = blockIdx.x * 256 + threadIdx.x;
  if (g >= n8) return;
  const float4* p = (const float4*)hs + (size_t)g * 2;
  float4 a = p[0], b = p[1];
  bf16x8 r;
#if USE_CVT
  r[0] = (__bf16)a.x; r[1] = (__bf16)a.y; r[2] = (__bf16)a.z; r[3] = (__bf16)a.w;
  r[4] = (__bf16)b.x; r[5] = (__bf16)b.y; r[6] = (__bf16)b.z; r[7] = (__bf16)b.w;
#else
  r[0] = (__bf16)a.x; r[1] = (__bf16)a.z; r[2] = (__bf16)b.x; r[3] = (__bf16)b.z;
  r[4] = (__bf16)a.y; r[5] = (__bf16)a.w; r[6] = (__bf16)b.y; r[7] = (__bf16)b.w;
#endif
  *(bf16x8*)(hsb + (size_t)g * 8) = r;
}

// ---------------- gate+up MFMA GEMM: B dequant in registers ----------------
// M=128 slots, N=128 (64 i x {gate,up}), BK=64, 512 thr = 8 waves (4 wr x 2 wc),
// wave tile 32x64. A in LDS (double-buffered, gll16, XOR-chunk swizzle); B per-lane regs.
__global__ __launch_bounds__(512, 2) void gemm_gate_up(
    const __bf16* __restrict__ hsb,
    const int* __restrict__ gblk, const int* __restrict__ gscl, const float* __restrict__ gbias,
    const int* __restrict__ ublk, const int* __restrict__ uscl, const float* __restrict__ ubias,
    const int* __restrict__ lists, const int* __restrict__ counts,
    const float* __restrict__ tw, const int* __restrict__ dk,
    const int* __restrict__ tab,
    __bf16* __restrict__ act, int T)
{
  int te = tab[blockIdx.x];
  if (te < 0) return;
  int e = te >> 16, mtile = te & 0xFFFF;
  int cnt = counts[e];
  int n_valid = cnt - mtile * 128;
  if (n_valid <= 0) return;
  if (n_valid > 128) n_valid = 128;
  int kk = *dk; if (kk > KMAX) kk = KMAX; if (kk < 1) kk = 1;

  __shared__ int s_tok[128];
  __shared__ char Abuf[2][16384];   // [row 0..127][phys chunk], phys = c ^ (row&7)

  int tid = threadIdx.x;
  if (tid < 128) {
    int idx = mtile * 128 + tid;
    s_tok[tid] = lists[e * T + (idx < cnt ? idx : mtile * 128)];
  }
  __syncthreads();

  int lane = tid & 63, w = tid >> 6;
  int r15 = lane & 15, kg = lane >> 4;
  int wr = w >> 1, wc = w & 1;

  // A staging: wave w stages rows [w*16, w*16+16), 2 gll16/lane, pre-swizzled source chunk
  int cA = (lane & 7) ^ (lane >> 3);
  unsigned aOff[2];
  #pragma unroll
  for (int q = 0; q < 2; ++q) {
    int row = w * 16 + q * 8 + (lane >> 3);
    int tok = s_tok[row] >> 3;
    aOff[q] = (unsigned)tok * (HH * 2) + (unsigned)cA * 16;
  }

  // B per-lane fragment sources: col (fn) -> matrix fn&1 (0=gate,1=up), i row
  int ibase = blockIdx.y * 64;
  const int4* bp[4]; const int* sp[4];
  #pragma unroll
  for (int fn = 0; fn < 4; ++fn) {
    int i_g = ibase + wc * 32 + (fn >> 1) * 16 + r15;
    const int* blkb = (fn & 1) ? ublk : gblk;
    const int* sclb = (fn & 1) ? uscl : gscl;
    bp[fn] = (const int4*)(blkb + ((size_t)e * II + i_g) * (HH / 2));
    sp[fn] = sclb + ((size_t)e * II + i_g) * (HH / 32);
  }

  f32x4 acc[2][4];
  #pragma unroll
  for (int a = 0; a < 2; ++a)
    #pragma unroll
    for (int b = 0; b < 4; ++b) acc[a][b] = (f32x4)0.f;

  bf16x8 bcur[4][2];
  int4 rw[4][2];
  int2 sc4[4];

  // ---- prologue (kt = 0) ----
  #pragma unroll
  for (int q = 0; q < 2; ++q)
    gll16((const char*)hsb + aOff[q], Abuf[0] + (w * 16 + q * 8) * 128 + lane * 16);
  #pragma unroll
  for (int fn = 0; fn < 4; ++fn) {
    #pragma unroll
    for (int kq = 0; kq < 2; ++kq) rw[fn][kq] = bp[fn][kq * 4 + kg];
    sc4[fn] = *(const int2*)(sp[fn]);
  }
  __syncthreads();
  #pragma unroll
  for (int fn = 0; fn < 4; ++fn) {
    bcur[fn][0] = decode_frag(rw[fn][0], sc4[fn].x);
    bcur[fn][1] = decode_frag(rw[fn][1], sc4[fn].y);
  }

  constexpr int NK = HH / 64;  // 16
  #pragma unroll 1
  for (int kt = 0; kt < NK; ++kt) {
    const char* Ac = Abuf[kt & 1];
    char* An = Abuf[(kt + 1) & 1];
    if (kt + 1 < NK) {
      #pragma unroll
      for (int q = 0; q < 2; ++q)
        gll16((const char*)hsb + aOff[q] + (kt + 1) * 128,
              An + (w * 16 + q * 8) * 128 + lane * 16);
      #pragma unroll
      for (int fn = 0; fn < 4; ++fn) {
        #pragma unroll
        for (int kq = 0; kq < 2; ++kq) rw[fn][kq] = bp[fn][(kt + 1) * 8 + kq * 4 + kg];
        sc4[fn] = *(const int2*)(sp[fn] + (kt + 1) * 2);
      }
    }
    // MFMA on current tile
    #pragma unroll
    for (int kq = 0; kq < 2; ++kq) {
      int kc = kq * 4 + kg;
      #pragma unroll
      for (int fm = 0; fm < 2; ++fm) {
        int m = wr * 32 + fm * 16 + r15;
        bf16x8 af = *(const bf16x8*)(Ac + m * 128 + ((kc ^ (m & 7)) * 16));
        #pragma unroll
        for (int fn = 0; fn < 4; ++fn)
          acc[fm][fn] = __builtin_amdgcn_mfma_f32_16x16x32_bf16(af, bcur[fn][kq], acc[fm][fn], 0, 0, 0);
      }
    }
    if (kt + 1 < NK) {
      #pragma unroll
      for (int fn = 0; fn < 4; ++fn) {
        bcur[fn][0] = decode_frag(rw[fn][0], sc4[fn].x);
        bcur[fn][1] = decode_frag(rw[fn][1], sc4[fn].y);
      }
    }
    __syncthreads();
  }

  // ---- epilogue: (gate,up) pairs in-lane, GLU + route weight, store bf16 ----
  #pragma unroll
  for (int fp = 0; fp < 2; ++fp) {
    int i_log = ibase + wc * 32 + fp * 16 + r15;
    float gb = gbias[e * II + i_log], ub = ubias[e * II + i_log];
#if USE_CVT
    int i_st = i_log;
#else
    int i_st = (i_log & ~7) | ((i_log & 1) << 2) | ((i_log & 7) >> 1);
#endif
    #pragma unroll
    for (int fm = 0; fm < 2; ++fm) {
      #pragma unroll
      for (int rg = 0; rg < 4; ++rg) {
        int mloc = wr * 32 + fm * 16 + kg * 4 + rg;
        if (mloc < n_valid) {
          int entry = s_tok[mloc];
          int t = entry >> 3, j = entry & 7;
          float wv = tw[t * kk + j];
          float g = fminf(acc[fm][fp * 2][rg] + gb, FLIMIT);
          float u = fminf(fmaxf(acc[fm][fp * 2 + 1][rg] + ub, -FLIMIT), FLIMIT);
          float glu = g / (1.f + __expf(-FALPHA * g));
          act[((size_t)t * kk + j) * II + i_st] = (__bf16)((u + 1.f) * glu * wv);
        }
      }
    }
  }
}

// ---------------- down MFMA GEMM: B dequant in registers ----------------
// M=64 slots, N=128 h, BK=64, 256 thr = 4 waves (2 wr x 2 wc), wave tile 32x64
__global__ __launch_bounds__(256, 2) void gemm_down(
    const __bf16* __restrict__ act,
    const int* __restrict__ dblk, const int* __restrict__ dscl,
    const int* __restrict__ lists, const int* __restrict__ counts,
    const int* __restrict__ dk, const int* __restrict__ tab,
    __bf16* __restrict__ partial, int T)
{
  int te = tab[blockIdx.x];
  if (te < 0) return;
  int e = te >> 16, mtile = te & 0xFFFF;
  int cnt = counts[e];
  int n_valid = cnt - mtile * 64;
  if (n_valid <= 0) return;
  if (n_valid > 64) n_valid = 64;
  int kk = *dk; if (kk > KMAX) kk = KMAX; if (kk < 1) kk = 1;

  __shared__ int s_tok[64];
  __shared__ char Abuf[2][8192];

  int tid = threadIdx.x;
  if (tid < 64) {
    int idx = mtile * 64 + tid;
    s_tok[tid] = lists[e * T + (idx < cnt ? idx : mtile * 64)];
  }
  __syncthreads();

  int lane = tid & 63, w = tid >> 6;
  int r15 = lane & 15, kg = lane >> 4;
  int wr = w >> 1, wc = w & 1;

  int cA = (lane & 7) ^ (lane >> 3);
  unsigned aOff[2];
  #pragma unroll
  for (int q = 0; q < 2; ++q) {
    int row = w * 16 + q * 8 + (lane >> 3);
    int entry = s_tok[row];
    unsigned slot = (unsigned)(entry >> 3) * kk + (entry & 7);
    aOff[q] = slot * (II * 2) + (unsigned)cA * 16;
  }

  int hbase = blockIdx.y * 128;
  const int4* bp[4]; const int* sp[4];
  #pragma unroll
  for (int fn = 0; fn < 4; ++fn) {
    int h = hbase + wc * 64 + fn * 16 + r15;
    bp[fn] = (const int4*)(dblk + ((size_t)e * HH + h) * (II / 2));
    sp[fn] = dscl + ((size_t)e * HH + h) * (II / 32);
  }

  f32x4 acc[2][4];
  #pragma unroll
  for (int a = 0; a < 2; ++a)
    #pragma unroll
    for (int b = 0; b < 4; ++b) acc[a][b] = (f32x4)0.f;

  bf16x8 bcur[4][2];
  int4 rw[4][2];
  int2 sc4[4];

  #pragma unroll
  for (int q = 0; q < 2; ++q)
    gll16((const char*)act + aOff[q], Abuf[0] + (w * 16 + q * 8) * 128 + lane * 16);
  #pragma unroll
  for (int fn = 0; fn < 4; ++fn) {
    #pragma unroll
    for (int kq = 0; kq < 2; ++kq) rw[fn][kq] = bp[fn][kq * 4 + kg];
    sc4[fn] = *(const int2*)(sp[fn]);
  }
  __syncthreads();
  #pragma unroll
  for (int fn = 0; fn < 4; ++fn) {
    bcur[fn][0] = decode_frag(rw[fn][0], sc4[fn].x);
    bcur[fn][1] = decode_frag(rw[fn][1], sc4[fn].y);
  }

  constexpr int NK = II / 64;  // 16
  #pragma unroll 1
  for (int kt = 0; kt < NK; ++kt) {
    const char* Ac = Abuf[kt & 1];
    char* An = Abuf[(kt + 1) & 1];
    if (kt + 1 < NK) {
      #pragma unroll
      for (int q = 0; q < 2; ++q)
        gll16((const char*)act + aOff[q] + (kt + 1) * 128,
              An + (w * 16 + q * 8) * 128 + lane * 16);
      #pragma unroll
      for (int fn = 0; fn < 4; ++fn) {
        #pragma unroll
        for (int kq = 0; kq < 2; ++kq) rw[fn][kq] = bp[fn][(kt + 1) * 8 + kq * 4 + kg];
        sc4[fn] = *(const int2*)(sp[fn] + (kt + 1) * 2);
      }
    }
    #pragma unroll
    for (int kq = 0; kq < 2; ++kq) {
      int kc = kq * 4 + kg;
      #pragma unroll
      for (int fm = 0; fm < 2; ++fm) {
        int m = wr * 32 + fm * 16 + r15;
        bf16x8 af = *(const bf16x8*)(Ac + m * 128 + ((kc ^ (m & 7)) * 16));
        #pragma unroll
        for (int fn = 0; fn < 4; ++fn)
          acc[fm][fn] = __builtin_amdgcn_mfma_f32_16x16x32_bf16(af, bcur[fn][kq], acc[fm][fn], 0, 0, 0);
      }
    }
    if (kt + 1 < NK) {
      #pragma unroll
      for (int fn = 0; fn < 4; ++fn) {
        bcur[fn][0] = decode_frag(rw[fn][0], sc4[fn].x);
        bcur[fn][1] = decode_frag(rw[fn][1], sc4[fn].y);
      }
    }
    __syncthreads();
  }

  #pragma unroll
  for (int fm = 0; fm < 2; ++fm) {
    #pragma unroll
    for (int rg = 0; rg < 4; ++rg) {
      int mloc = wr * 32 + fm * 16 + kg * 4 + rg;
      if (mloc < n_valid) {
        int entry = s_tok[mloc];
        int t = entry >> 3, j = entry & 7;
        size_t slot = (size_t)t * kk + j;
        #pragma unroll
        for (int fn = 0; fn < 4; ++fn) {
          int h = hbase + wc * 64 + fn * 16 + r15;
          partial[slot * HH + h] = (__bf16)acc[fm][fn][rg];
        }
      }
    }
  }
}

// ---------------- combine ----------------
__global__ void combine_kernel(const __bf16* __restrict__ partial, const float* __restrict__ route,
                               const float* __restrict__ dbias, const int* __restrict__ dk,
                               float* __restrict__ out, int E) {
  int t = blockIdx.y;
  int h = blockIdx.x * 256 + threadIdx.x;
  int kk = *dk; if (kk > KMAX) kk = KMAX; if (kk < 1) kk = 1;
  float s = 0.f;
  for (int j = 0; j < kk; ++j) s += (float)partial[((size_t)t * kk + j) * HH + h];
  for (int e = 0; e < E; ++e) s += route[t * E + e] * dbias[(size_t)e * HH + h];
  out[(size_t)t * HH + h] = s;
}

extern "C" void kernel_launch(void* const* d_in, const int* in_sizes, int n_in,
                              void* d_out, int out_size, void* d_ws, size_t ws_size,
                              hipStream_t stream) {
  const float* hs    = (const float*)d_in[0];
  const float* rl    = (const float*)d_in[1];
  const int*   gblk  = (const int*)d_in[2];
  const int*   gscl  = (const int*)d_in[3];
  const float* gbias = (const float*)d_in[4];
  const int*   ublk  = (const int*)d_in[5];
  const int*   uscl  = (const int*)d_in[6];
  const float* ubias = (const float*)d_in[7];
  const int*   dblk  = (const int*)d_in[8];
  const int*   dscl  = (const int*)d_in[9];
  const float* dbias = (const float*)d_in[10];
  const int*   dk    = (const int*)d_in[11];

  long s0 = in_sizes[0], s1 = in_sizes[1], s2 = in_sizes[2], s4 = in_sizes[4];
  int H = (int)(2 * s2 / s4);       // = 1024
  int T = (int)(s0 / H);            // = 1024
  int E = (int)(s1 / T);            // = 8

  char* w = (char*)d_ws;
  auto alloc = [&](size_t bytes) { char* p = w; w += (bytes + 255) & ~size_t(255); return p; };
  float*  route   = (float*)alloc(sizeof(float) * (size_t)T * E);
  int*    tidx    = (int*)  alloc(sizeof(int)   * (size_t)T * KMAX);
  float*  twp     = (float*)alloc(sizeof(float) * (size_t)T * KMAX);
  int*    counts  = (int*)  alloc(sizeof(int)   * (size_t)E);
  int*    lists   = (int*)  alloc(sizeof(int)   * (size_t)E * T);
  int*    tabGU   = (int*)  alloc(sizeof(int)   * GU_TILES);
  int*    tabDN   = (int*)  alloc(sizeof(int)   * DN_TILES);
  __bf16* hsb     = (__bf16*)alloc(sizeof(__bf16) * (size_t)T * HH);
  __bf16* act     = (__bf16*)alloc(sizeof(__bf16) * (size_t)T * KMAX * II);
  __bf16* partial = (__bf16*)alloc(sizeof(__bf16) * (size_t)T * KMAX * HH);

  routing_kernel<<<dim3((T + 255) / 256), 256, 0, stream>>>(rl, dk, T, E, route, tidx, twp);
  build_lists<<<dim3(E), 64, 0, stream>>>(tidx, dk, T, lists, counts);
  build_tiles<<<dim3(1), 64, 0, stream>>>(counts, E, tabGU, tabDN);
  convert_hs<<<dim3((T * HH / 8 + 255) / 256), 256, 0, stream>>>(hs, hsb, T * HH / 8);
  gemm_gate_up<<<dim3(GU_TILES, II / 64), 512, 0, stream>>>(
      hsb, gblk, gscl, gbias, ublk, uscl, ubias, lists, counts, twp, dk, tabGU, act, T);
  gemm_down<<<dim3(DN_TILES, HH / 128), 256, 0, stream>>>(
      act, dblk, dscl, lists, counts, dk, tabDN, partial, T);
  combine_kernel<<<dim3(HH / 256, T), 256, 0, stream>>>(partial, route, dbias, dk, (float*)d_out, E);
}

// Round 5
// 91.177 us; speedup vs baseline: 2.2723x; 2.2723x over previous
//
#include <hip/hip_runtime.h>
#include <cstdint>
#include <cstddef>

typedef __bf16 bf16x8 __attribute__((ext_vector_type(8)));
typedef __bf16 bf16x2 __attribute__((ext_vector_type(2)));
typedef float f32x4 __attribute__((ext_vector_type(4)));
typedef unsigned short u16x2 __attribute__((ext_vector_type(2)));

constexpr int HH = 1024;   // hidden dim
constexpr int II = 1024;   // intermediate dim
constexpr int KMAX = 2;
constexpr int EMAX = 8;
constexpr int GU_TILES = 24;   // >= sum ceil(cnt_e/128) worst case
constexpr int DN_TILES = 40;   // >= sum ceil(cnt_e/64) worst case
constexpr float FALPHA = 1.702f;
constexpr float FLIMIT = 7.0f;

#if __has_builtin(__builtin_amdgcn_cvt_scalef32_pk_bf16_fp4)
#define USE_CVT 1
#else
#define USE_CVT 0
#endif

// ---- fallback perm decode (k-order within 8-group permuted [0,2,4,6,1,3,5,7]) ----
__device__ __forceinline__ unsigned pk_add16(unsigned a, unsigned b) {
  u16x2 x, y;
  __builtin_memcpy(&x, &a, 4); __builtin_memcpy(&y, &b, 4);
  u16x2 r = x + y;
  unsigned o; __builtin_memcpy(&o, &r, 4); return o;
}
__device__ __forceinline__ int4 decode_chunk(int4 raw, unsigned addk) {
  unsigned p = (unsigned)raw.x | ((unsigned)raw.y << 8) |
               ((unsigned)raw.z << 16) | ((unsigned)raw.w << 24);
  unsigned q = p >> 4;
  unsigned me = p & 0x07070707u, mo = q & 0x07070707u;
  unsigned se = p & 0x08080808u, so = q & 0x08080808u;
  unsigned hiE = __builtin_amdgcn_perm(0x40404040u, 0x3F3F3F14u, me) | (se << 4);
  unsigned hiO = __builtin_amdgcn_perm(0x40404040u, 0x3F3F3F14u, mo) | (so << 4);
  unsigned loE = __builtin_amdgcn_perm(0xC0804000u, 0xC0800000u, me);
  unsigned loO = __builtin_amdgcn_perm(0xC0804000u, 0xC0800000u, mo);
  int4 out;
  out.x = (int)pk_add16(__builtin_amdgcn_perm(hiE, loE, 0x05010400u), addk);
  out.y = (int)pk_add16(__builtin_amdgcn_perm(hiE, loE, 0x07030602u), addk);
  out.z = (int)pk_add16(__builtin_amdgcn_perm(hiO, loO, 0x05010400u), addk);
  out.w = (int)pk_add16(__builtin_amdgcn_perm(hiO, loO, 0x07030602u), addk);
  return out;
}
__device__ __forceinline__ unsigned make_addk(int s) {
  int k = s - 127;
  unsigned t = ((unsigned)(k << 7)) & 0xFFFFu;
  return t | (t << 16);
}

// raw chunk (8 fp4 as int32-per-byte) + e8m0 scale -> bf16x8 fragment
__device__ __forceinline__ bf16x8 decode_frag(int4 raw, int s) {
#if USE_CVT
  unsigned t0 = __builtin_amdgcn_perm((unsigned)raw.y, (unsigned)raw.x, 0x00000400u);
  unsigned t1 = __builtin_amdgcn_perm((unsigned)raw.w, (unsigned)raw.z, 0x00000400u);
  unsigned p  = __builtin_amdgcn_perm(t1, t0, 0x05040100u);
  float scf = __uint_as_float((unsigned)s << 23);
  bf16x2 a = __builtin_amdgcn_cvt_scalef32_pk_bf16_fp4(p, scf, 0);
  bf16x2 b = __builtin_amdgcn_cvt_scalef32_pk_bf16_fp4(p, scf, 1);
  bf16x2 c = __builtin_amdgcn_cvt_scalef32_pk_bf16_fp4(p, scf, 2);
  bf16x2 d = __builtin_amdgcn_cvt_scalef32_pk_bf16_fp4(p, scf, 3);
  bf16x8 r;
  r[0]=a[0]; r[1]=a[1]; r[2]=b[0]; r[3]=b[1]; r[4]=c[0]; r[5]=c[1]; r[6]=d[0]; r[7]=d[1];
  return r;
#else
  int4 d4 = decode_chunk(raw, make_addk(s));
  bf16x8 r; __builtin_memcpy(&r, &d4, 16);
  return r;
#endif
}

__device__ __forceinline__ void gll16(const void* g, void* l) {
  __builtin_amdgcn_global_load_lds(
      (const __attribute__((address_space(1))) void*)g,
      (__attribute__((address_space(3))) void*)l, 16, 0, 0);
}

// ---------------- routing ----------------
__global__ void routing_kernel(const float* __restrict__ logits, const int* __restrict__ dk,
                               int T, int E, float* __restrict__ route,
                               int* __restrict__ tidx, float* __restrict__ tw) {
  int t = blockIdx.x * blockDim.x + threadIdx.x;
  if (t >= T) return;
  int kk = *dk; if (kk > KMAX) kk = KMAX; if (kk < 1) kk = 1;
  int EE = E > EMAX ? EMAX : E;
  float v[EMAX]; bool used[EMAX];
  for (int e = 0; e < EE; ++e) { v[e] = logits[t * E + e]; used[e] = false; route[t * E + e] = 0.f; }
  float tv[KMAX]; int ti[KMAX];
  for (int j = 0; j < kk; ++j) {
    float best = -3.4e38f; int bi = 0;
    for (int e = 0; e < EE; ++e) if (!used[e] && v[e] > best) { best = v[e]; bi = e; }
    used[bi] = true; tv[j] = best; ti[j] = bi;
  }
  float mx = tv[0], ssum = 0.f, wj[KMAX];
  for (int j = 0; j < kk; ++j) { wj[j] = __expf(tv[j] - mx); ssum += wj[j]; }
  for (int j = 0; j < kk; ++j) {
    float wv = wj[j] / ssum;
    route[t * E + ti[j]] = wv;
    tidx[t * kk + j] = ti[j];
    tw[t * kk + j] = wv;
  }
}

__global__ void build_lists(const int* __restrict__ tidx, const int* __restrict__ dk,
                            int T, int* __restrict__ lists, int* __restrict__ counts) {
  int e = blockIdx.x;
  int lane = threadIdx.x;
  int kk = *dk; if (kk > KMAX) kk = KMAX; if (kk < 1) kk = 1;
  int cnt = 0;
  for (int base = 0; base < T; base += 64) {
    int t = base + lane;
    int j = -1;
    if (t < T) {
      for (int q = 0; q < kk; ++q) if (tidx[t * kk + q] == e) j = q;
    }
    unsigned long long m = __ballot(j >= 0);
    if (j >= 0) {
      int pre = __popcll(m & ((1ull << lane) - 1ull));
      lists[e * T + cnt + pre] = (t << 3) | j;
    }
    cnt += __popcll(m);
  }
  if (lane == 0) counts[e] = cnt;
}

__global__ void build_tiles(const int* __restrict__ counts, int E,
                            int* __restrict__ tabGU, int* __restrict__ tabDN) {
  if (threadIdx.x == 0 && blockIdx.x == 0) {
    int g = 0, d = 0;
    for (int e = 0; e < E && e < EMAX; ++e) {
      int c = counts[e];
      for (int m = 0; m * 128 < c && g < GU_TILES; ++m) tabGU[g++] = (e << 16) | m;
      for (int m = 0; m * 64 < c && d < DN_TILES; ++m) tabDN[d++] = (e << 16) | m;
    }
    for (; g < GU_TILES; ++g) tabGU[g] = -1;
    for (; d < DN_TILES; ++d) tabDN[d] = -1;
  }
}

// ---------------- hs fp32 -> bf16 ----------------
__global__ void convert_hs(const float* __restrict__ hs, __bf16* __restrict__ hsb, int n8) {
  int g = blockIdx.x * 256 + threadIdx.x;
  if (g >= n8) return;
  const float4* p = (const float4*)hs + (size_t)g * 2;
  float4 a = p[0], b = p[1];
  bf16x8 r;
#if USE_CVT
  r[0] = (__bf16)a.x; r[1] = (__bf16)a.y; r[2] = (__bf16)a.z; r[3] = (__bf16)a.w;
  r[4] = (__bf16)b.x; r[5] = (__bf16)b.y; r[6] = (__bf16)b.z; r[7] = (__bf16)b.w;
#else
  r[0] = (__bf16)a.x; r[1] = (__bf16)a.z; r[2] = (__bf16)b.x; r[3] = (__bf16)b.z;
  r[4] = (__bf16)a.y; r[5] = (__bf16)a.w; r[6] = (__bf16)b.y; r[7] = (__bf16)b.w;
#endif
  *(bf16x8*)(hsb + (size_t)g * 8) = r;
}

// ---------------- gate+up GEMM: A + raw-B both via gll16, decode in regs ----------------
// M=128 slots, N=64 (32 i x {gate,up}), BK=64, 256 thr = 4 waves (2x2), wave tile 64x32
__global__ __launch_bounds__(256, 2) void gemm_gate_up(
    const __bf16* __restrict__ hsb,
    const int* __restrict__ gblk, const int* __restrict__ gscl, const float* __restrict__ gbias,
    const int* __restrict__ ublk, const int* __restrict__ uscl, const float* __restrict__ ubias,
    const int* __restrict__ lists, const int* __restrict__ counts,
    const float* __restrict__ tw, const int* __restrict__ dk,
    const int* __restrict__ tab,
    __bf16* __restrict__ act, int T)
{
  int te = tab[blockIdx.x];
  if (te < 0) return;
  int e = te >> 16, mtile = te & 0xFFFF;
  int cnt = counts[e];
  int n_valid = cnt - mtile * 128;
  if (n_valid <= 0) return;
  if (n_valid > 128) n_valid = 128;
  int kk = *dk; if (kk > KMAX) kk = KMAX; if (kk < 1) kk = 1;

  __shared__ int s_tok[128];
  __shared__ char Abuf[2][16384];   // [row 0..127][chunk^(row&7)]*16B
  __shared__ char Braw[2][8192];    // [row 0..63][chunk^(row&7)]*16B, raw fp4-inflated

  int tid = threadIdx.x;
  if (tid < 128) {
    int idx = mtile * 128 + tid;
    s_tok[tid] = lists[e * T + (idx < cnt ? idx : mtile * 128)];
  }
  __syncthreads();

  int lane = tid & 63, w = tid >> 6;
  int r15 = lane & 15, kg = lane >> 4;
  int wr = w >> 1, wc = w & 1;
  int cA = (lane & 7) ^ (lane >> 3);

  // A staging: rows w*32+q*8+(lane>>3), q=0..3
  unsigned aOff[4];
  #pragma unroll
  for (int q = 0; q < 4; ++q) {
    int row = w * 32 + q * 8 + (lane >> 3);
    int tok = s_tok[row] >> 3;
    aOff[q] = (unsigned)tok * (HH * 2) + (unsigned)cA * 16;
  }

  // B staging: rows w*16+q*8+(lane>>3), q=0..1 (64 B-rows = 32 i x {gate,up})
  int ibase = blockIdx.y * 32;
  const char* bSrc[2];
  #pragma unroll
  for (int q = 0; q < 2; ++q) {
    int row = w * 16 + q * 8 + (lane >> 3);
    int mat = (row >> 4) & 1;
    int i = ibase + ((row >> 5) << 4) + (row & 15);
    const int* base = mat ? ublk : gblk;
    bSrc[q] = (const char*)(base + ((size_t)e * II + i) * (HH / 2)) + cA * 16;
  }

  // per-lane scale pointers: col n = wc*32 + fn*16 + r15 -> mat=fn, i = ibase+wc*16+r15
  const int* sp[2];
  {
    int i = ibase + wc * 16 + r15;
    sp[0] = gscl + ((size_t)e * II + i) * (HH / 32);
    sp[1] = uscl + ((size_t)e * II + i) * (HH / 32);
  }

  f32x4 acc[4][2];
  #pragma unroll
  for (int a = 0; a < 4; ++a) { acc[a][0] = (f32x4)0.f; acc[a][1] = (f32x4)0.f; }

  // prologue
  #pragma unroll
  for (int q = 0; q < 4; ++q)
    gll16((const char*)hsb + aOff[q], Abuf[0] + (w * 32 + q * 8) * 128 + lane * 16);
  #pragma unroll
  for (int q = 0; q < 2; ++q)
    gll16(bSrc[q], Braw[0] + (w * 16 + q * 8) * 128 + lane * 16);
  int2 scv[2];
  scv[0] = *(const int2*)(sp[0]);
  scv[1] = *(const int2*)(sp[1]);
  __syncthreads();

  constexpr int NK = HH / 64;  // 16
  #pragma unroll 1
  for (int kt = 0; kt < NK; ++kt) {
    const char* Ac = Abuf[kt & 1];
    const char* Bc = Braw[kt & 1];
    int2 scn[2];
    if (kt + 1 < NK) {
      char* An = Abuf[(kt + 1) & 1];
      char* Bn = Braw[(kt + 1) & 1];
      #pragma unroll
      for (int q = 0; q < 4; ++q)
        gll16((const char*)hsb + aOff[q] + (kt + 1) * 128,
              An + (w * 32 + q * 8) * 128 + lane * 16);
      #pragma unroll
      for (int q = 0; q < 2; ++q)
        gll16(bSrc[q] + (kt + 1) * 128, Bn + (w * 16 + q * 8) * 128 + lane * 16);
      scn[0] = *(const int2*)(sp[0] + (kt + 1) * 2);
      scn[1] = *(const int2*)(sp[1] + (kt + 1) * 2);
    }
    // decode current B fragments from raw LDS
    bf16x8 bfr[2][2];
    #pragma unroll
    for (int fn = 0; fn < 2; ++fn) {
      int n = wc * 32 + fn * 16 + r15;
      #pragma unroll
      for (int kq = 0; kq < 2; ++kq) {
        int kc = kq * 4 + kg;
        int4 raw = *(const int4*)(Bc + n * 128 + ((kc ^ (n & 7)) * 16));
        bfr[fn][kq] = decode_frag(raw, kq ? scv[fn].y : scv[fn].x);
      }
    }
    // MFMA
    #pragma unroll
    for (int kq = 0; kq < 2; ++kq) {
      int kc = kq * 4 + kg;
      #pragma unroll
      for (int fm = 0; fm < 4; ++fm) {
        int m = wr * 64 + fm * 16 + r15;
        bf16x8 af = *(const bf16x8*)(Ac + m * 128 + ((kc ^ (m & 7)) * 16));
        acc[fm][0] = __builtin_amdgcn_mfma_f32_16x16x32_bf16(af, bfr[0][kq], acc[fm][0], 0, 0, 0);
        acc[fm][1] = __builtin_amdgcn_mfma_f32_16x16x32_bf16(af, bfr[1][kq], acc[fm][1], 0, 0, 0);
      }
    }
    scv[0] = scn[0]; scv[1] = scn[1];
    __syncthreads();
  }

  // epilogue: gate=acc[.][0], up=acc[.][1], same i per lane
  int i_log = ibase + wc * 16 + r15;
  float gb = gbias[e * II + i_log], ub = ubias[e * II + i_log];
#if USE_CVT
  int i_st = i_log;
#else
  int i_st = (i_log & ~7) | ((i_log & 1) << 2) | ((i_log & 7) >> 1);
#endif
  #pragma unroll
  for (int fm = 0; fm < 4; ++fm) {
    #pragma unroll
    for (int rg = 0; rg < 4; ++rg) {
      int mloc = wr * 64 + fm * 16 + kg * 4 + rg;
      if (mloc < n_valid) {
        int entry = s_tok[mloc];
        int t = entry >> 3, j = entry & 7;
        float wv = tw[t * kk + j];
        float g = fminf(acc[fm][0][rg] + gb, FLIMIT);
        float u = fminf(fmaxf(acc[fm][1][rg] + ub, -FLIMIT), FLIMIT);
        float glu = g / (1.f + __expf(-FALPHA * g));
        act[((size_t)t * kk + j) * II + i_st] = (__bf16)((u + 1.f) * glu * wv);
      }
    }
  }
}

// ---------------- down GEMM: same staging scheme ----------------
// M=64 slots, N=64 h, BK=64, 256 thr = 4 waves (2x2), wave tile 32x32
__global__ __launch_bounds__(256, 2) void gemm_down(
    const __bf16* __restrict__ act,
    const int* __restrict__ dblk, const int* __restrict__ dscl,
    const int* __restrict__ lists, const int* __restrict__ counts,
    const int* __restrict__ dk, const int* __restrict__ tab,
    __bf16* __restrict__ partial, int T)
{
  int te = tab[blockIdx.x];
  if (te < 0) return;
  int e = te >> 16, mtile = te & 0xFFFF;
  int cnt = counts[e];
  int n_valid = cnt - mtile * 64;
  if (n_valid <= 0) return;
  if (n_valid > 64) n_valid = 64;
  int kk = *dk; if (kk > KMAX) kk = KMAX; if (kk < 1) kk = 1;

  __shared__ int s_tok[64];
  __shared__ char Abuf[2][8192];
  __shared__ char Braw[2][8192];

  int tid = threadIdx.x;
  if (tid < 64) {
    int idx = mtile * 64 + tid;
    s_tok[tid] = lists[e * T + (idx < cnt ? idx : mtile * 64)];
  }
  __syncthreads();

  int lane = tid & 63, w = tid >> 6;
  int r15 = lane & 15, kg = lane >> 4;
  int wr = w >> 1, wc = w & 1;
  int cA = (lane & 7) ^ (lane >> 3);

  unsigned aOff[2];
  #pragma unroll
  for (int q = 0; q < 2; ++q) {
    int row = w * 16 + q * 8 + (lane >> 3);
    int entry = s_tok[row];
    unsigned slot = (unsigned)(entry >> 3) * kk + (entry & 7);
    aOff[q] = slot * (II * 2) + (unsigned)cA * 16;
  }

  int hbase = blockIdx.y * 64;
  const char* bSrc[2];
  #pragma unroll
  for (int q = 0; q < 2; ++q) {
    int row = w * 16 + q * 8 + (lane >> 3);
    int h = hbase + row;
    bSrc[q] = (const char*)(dblk + ((size_t)e * HH + h) * (II / 2)) + cA * 16;
  }

  const int* sp[2];
  #pragma unroll
  for (int fn = 0; fn < 2; ++fn) {
    int h = hbase + wc * 32 + fn * 16 + r15;
    sp[fn] = dscl + ((size_t)e * HH + h) * (II / 32);
  }

  f32x4 acc[2][2];
  #pragma unroll
  for (int a = 0; a < 2; ++a) { acc[a][0] = (f32x4)0.f; acc[a][1] = (f32x4)0.f; }

  #pragma unroll
  for (int q = 0; q < 2; ++q)
    gll16((const char*)act + aOff[q], Abuf[0] + (w * 16 + q * 8) * 128 + lane * 16);
  #pragma unroll
  for (int q = 0; q < 2; ++q)
    gll16(bSrc[q], Braw[0] + (w * 16 + q * 8) * 128 + lane * 16);
  int2 scv[2];
  scv[0] = *(const int2*)(sp[0]);
  scv[1] = *(const int2*)(sp[1]);
  __syncthreads();

  constexpr int NK = II / 64;  // 16
  #pragma unroll 1
  for (int kt = 0; kt < NK; ++kt) {
    const char* Ac = Abuf[kt & 1];
    const char* Bc = Braw[kt & 1];
    int2 scn[2];
    if (kt + 1 < NK) {
      char* An = Abuf[(kt + 1) & 1];
      char* Bn = Braw[(kt + 1) & 1];
      #pragma unroll
      for (int q = 0; q < 2; ++q)
        gll16((const char*)act + aOff[q] + (kt + 1) * 128,
              An + (w * 16 + q * 8) * 128 + lane * 16);
      #pragma unroll
      for (int q = 0; q < 2; ++q)
        gll16(bSrc[q] + (kt + 1) * 128, Bn + (w * 16 + q * 8) * 128 + lane * 16);
      scn[0] = *(const int2*)(sp[0] + (kt + 1) * 2);
      scn[1] = *(const int2*)(sp[1] + (kt + 1) * 2);
    }
    bf16x8 bfr[2][2];
    #pragma unroll
    for (int fn = 0; fn < 2; ++fn) {
      int n = wc * 32 + fn * 16 + r15;
      #pragma unroll
      for (int kq = 0; kq < 2; ++kq) {
        int kc = kq * 4 + kg;
        int4 raw = *(const int4*)(Bc + n * 128 + ((kc ^ (n & 7)) * 16));
        bfr[fn][kq] = decode_frag(raw, kq ? scv[fn].y : scv[fn].x);
      }
    }
    #pragma unroll
    for (int kq = 0; kq < 2; ++kq) {
      int kc = kq * 4 + kg;
      #pragma unroll
      for (int fm = 0; fm < 2; ++fm) {
        int m = wr * 32 + fm * 16 + r15;
        bf16x8 af = *(const bf16x8*)(Ac + m * 128 + ((kc ^ (m & 7)) * 16));
        acc[fm][0] = __builtin_amdgcn_mfma_f32_16x16x32_bf16(af, bfr[0][kq], acc[fm][0], 0, 0, 0);
        acc[fm][1] = __builtin_amdgcn_mfma_f32_16x16x32_bf16(af, bfr[1][kq], acc[fm][1], 0, 0, 0);
      }
    }
    scv[0] = scn[0]; scv[1] = scn[1];
    __syncthreads();
  }

  #pragma unroll
  for (int fm = 0; fm < 2; ++fm) {
    #pragma unroll
    for (int rg = 0; rg < 4; ++rg) {
      int mloc = wr * 32 + fm * 16 + kg * 4 + rg;
      if (mloc < n_valid) {
        int entry = s_tok[mloc];
        int t = entry >> 3, j = entry & 7;
        size_t slot = (size_t)t * kk + j;
        #pragma unroll
        for (int fn = 0; fn < 2; ++fn) {
          int h = hbase + wc * 32 + fn * 16 + r15;
          partial[slot * HH + h] = (__bf16)acc[fm][fn][rg];
        }
      }
    }
  }
}

// ---------------- combine ----------------
__global__ void combine_kernel(const __bf16* __restrict__ partial, const float* __restrict__ route,
                               const float* __restrict__ dbias, const int* __restrict__ dk,
                               float* __restrict__ out, int E) {
  int t = blockIdx.y;
  int h = blockIdx.x * 256 + threadIdx.x;
  int kk = *dk; if (kk > KMAX) kk = KMAX; if (kk < 1) kk = 1;
  float s = 0.f;
  for (int j = 0; j < kk; ++j) s += (float)partial[((size_t)t * kk + j) * HH + h];
  for (int e = 0; e < E; ++e) s += route[t * E + e] * dbias[(size_t)e * HH + h];
  out[(size_t)t * HH + h] = s;
}

extern "C" void kernel_launch(void* const* d_in, const int* in_sizes, int n_in,
                              void* d_out, int out_size, void* d_ws, size_t ws_size,
                              hipStream_t stream) {
  const float* hs    = (const float*)d_in[0];
  const float* rl    = (const float*)d_in[1];
  const int*   gblk  = (const int*)d_in[2];
  const int*   gscl  = (const int*)d_in[3];
  const float* gbias = (const float*)d_in[4];
  const int*   ublk  = (const int*)d_in[5];
  const int*   uscl  = (const int*)d_in[6];
  const float* ubias = (const float*)d_in[7];
  const int*   dblk  = (const int*)d_in[8];
  const int*   dscl  = (const int*)d_in[9];
  const float* dbias = (const float*)d_in[10];
  const int*   dk    = (const int*)d_in[11];

  long s0 = in_sizes[0], s1 = in_sizes[1], s2 = in_sizes[2], s4 = in_sizes[4];
  int H = (int)(2 * s2 / s4);       // = 1024
  int T = (int)(s0 / H);            // = 1024
  int E = (int)(s1 / T);            // = 8

  char* w = (char*)d_ws;
  auto alloc = [&](size_t bytes) { char* p = w; w += (bytes + 255) & ~size_t(255); return p; };
  float*  route   = (float*)alloc(sizeof(float) * (size_t)T * E);
  int*    tidx    = (int*)  alloc(sizeof(int)   * (size_t)T * KMAX);
  float*  twp     = (float*)alloc(sizeof(float) * (size_t)T * KMAX);
  int*    counts  = (int*)  alloc(sizeof(int)   * (size_t)E);
  int*    lists   = (int*)  alloc(sizeof(int)   * (size_t)E * T);
  int*    tabGU   = (int*)  alloc(sizeof(int)   * GU_TILES);
  int*    tabDN   = (int*)  alloc(sizeof(int)   * DN_TILES);
  __bf16* hsb     = (__bf16*)alloc(sizeof(__bf16) * (size_t)T * HH);
  __bf16* act     = (__bf16*)alloc(sizeof(__bf16) * (size_t)T * KMAX * II);
  __bf16* partial = (__bf16*)alloc(sizeof(__bf16) * (size_t)T * KMAX * HH);

  routing_kernel<<<dim3((T + 255) / 256), 256, 0, stream>>>(rl, dk, T, E, route, tidx, twp);
  build_lists<<<dim3(E), 64, 0, stream>>>(tidx, dk, T, lists, counts);
  build_tiles<<<dim3(1), 64, 0, stream>>>(counts, E, tabGU, tabDN);
  convert_hs<<<dim3((T * HH / 8 + 255) / 256), 256, 0, stream>>>(hs, hsb, T * HH / 8);
  gemm_gate_up<<<dim3(GU_TILES, II / 32), 256, 0, stream>>>(
      hsb, gblk, gscl, gbias, ublk, uscl, ubias, lists, counts, twp, dk, tabGU, act, T);
  gemm_down<<<dim3(DN_TILES, HH / 64), 256, 0, stream>>>(
      act, dblk, dscl, lists, counts, dk, tabDN, partial, T);
  combine_kernel<<<dim3(HH / 256, T), 256, 0, stream>>>(partial, route, dbias, dk, (float*)d_out, E);
}